// Round 8
// baseline (205.525 us; speedup 1.0000x reference)
//
#include <hip/hip_runtime.h>
#include <math.h>

// Problem constants
#define NTOT 4096        // H*W = 64*64
#define NBATCH 8
#define CIN 128
#define CK 64
#define CV 64
#define CO 128
#define BN_COUNT 32768.0f // B*H*W

// Workspace layout (float offsets).
// stats: [(which*64+c)*16] sum, +4 sumsq  (line-exclusive per channel)
// vsum : [(b*64+v)*16]                    (line-exclusive per (b,v))
// M,d  : aliased into dead Yk region (Yk last read by kv_kernel; m_kernel after)
// KVp  : 64-chunk partials of KV in d_out scratch (overwritten by out_kernel)
#define OFF_YQ    0ul
#define OFF_YK    2097152ul
#define OFF_V     4194304ul
#define OFF_STATS 6291456ul           // 2*64*16 = 2048 floats
#define OFF_VSUM  6293504ul           // 8*64*16 = 8192 floats
#define OFF_M     2097152ul           // = OFF_YK, [b][64][128] = 65536 floats
#define OFF_D     2162688ul           // [b][128] = 1024 floats

// ---------------------------------------------------------------------------
// Kernel 1: LDS-staged 1x1-conv GEMM. Round-8 change: inner loop split into
// (a) batched x[32] register-cache from LDS (one lgkm drain per 32-chunk) and
// (b) pure scalar-stream FMA phase where each ki's 32 W values are CONTIGUOUS
// (s_load_dwordx4/x8 instead of 16 scattered dwords per c). Fixes the
// lgkmcnt-mixing stall (s_load and ds_read share lgkmcnt, complete OOO ->
// per-c drains in the old loop). grid (64, 8, 3), block 256.
// ---------------------------------------------------------------------------
__global__ __launch_bounds__(256) void gemm3_kernel(
    const float* __restrict__ Xq, const float* __restrict__ Xk, const float* __restrict__ Xv,
    const float* __restrict__ Wk, const float* __restrict__ bk,
    const float* __restrict__ Wv, const float* __restrict__ bv,
    float* __restrict__ Yq, float* __restrict__ Yk, float* __restrict__ Vv)
{
    const int chunk = blockIdx.x;
    const int b     = blockIdx.y;
    const int which = blockIdx.z;
    const float* X    = (which == 0) ? Xq : (which == 1) ? Xk : Xv;
    const float* W    = (which == 2) ? Wv : Wk;
    const float* bias = (which == 2) ? bv : bk;
    float* Y          = (which == 0) ? Yq : (which == 1) ? Yk : Vv;

    __shared__ float sX[CIN][64];   // 32 KB

    const int t = threadIdx.x;
    const int lane = t & 63;
    const int wu = __builtin_amdgcn_readfirstlane(t >> 6);  // wave id, uniform

    const int n0 = chunk * 64;
    const float* Xb = X + (size_t)b * (CIN * NTOT) + n0;

#pragma unroll
    for (int r = 0; r < 8; ++r) {
        int idx4 = t + r * 256;           // 0..2047
        int c  = idx4 >> 4;               // 0..127
        int j4 = (idx4 & 15) << 2;        // 0..60
        float4 xv = *(const float4*)(Xb + (size_t)c * NTOT + j4);
        *(float4*)&sX[c][j4] = xv;
    }
    __syncthreads();

    const float* Wp = W + (size_t)wu * 16 * CIN;
    float acc[16];
#pragma unroll
    for (int ki = 0; ki < 16; ++ki) acc[ki] = 0.f;

#pragma unroll
    for (int cb = 0; cb < 4; ++cb) {
        // (a) batch 32 LDS reads into registers -> single lgkm drain
        float x[32];
#pragma unroll
        for (int i = 0; i < 32; ++i) x[i] = sX[cb * 32 + i][lane];
        // (b) pure scalar stream: per ki, 32 contiguous W floats (wide s_load)
#pragma unroll
        for (int ki = 0; ki < 16; ++ki) {
            const float* wrow = Wp + ki * CIN + cb * 32;   // wave-uniform, contiguous
            float a0 = 0.f, a1 = 0.f;
#pragma unroll
            for (int i = 0; i < 32; i += 2) {
                a0 += x[i]     * wrow[i];
                a1 += x[i + 1] * wrow[i + 1];
            }
            acc[ki] += a0 + a1;
        }
    }

    float* Yb = Y + (size_t)b * (CK * NTOT) + n0;
#pragma unroll
    for (int ki = 0; ki < 16; ++ki) {
        int o = wu * 16 + ki;
        Yb[(size_t)o * NTOT + lane] = acc[ki] + bias[o];
    }
}

// ---------------------------------------------------------------------------
// Kernel 2: BN batch stats. grid (8 n-splits, 64 c, 2 tensors) = 1024 blocks;
// 16KB coalesced per block, block-reduce, 2 padded atomics (16 ops/line).
// ---------------------------------------------------------------------------
__global__ __launch_bounds__(256) void stats_kernel(
    const float* __restrict__ Yq, const float* __restrict__ Yk,
    float* __restrict__ stats)
{
    const int nsplit = blockIdx.x;   // 0..7
    const int c      = blockIdx.y;   // 0..63
    const int which  = blockIdx.z;   // 0..1
    const float* Y = which ? Yk : Yq;
    const int t = threadIdx.x;

    float s = 0.f, ss = 0.f;
#pragma unroll
    for (int p = 0; p < 4; ++p) {
        int b = (t >> 7) + p * 2;        // 2 batches per pass
        int e = (t & 127) << 2;          // 0..508
        const float* src = Y + (size_t)b * (CK * NTOT) + (size_t)c * NTOT
                         + nsplit * 512 + e;
        float4 v = *(const float4*)src;
        s  += v.x + v.y + v.z + v.w;
        ss += v.x * v.x + v.y * v.y + v.z * v.z + v.w * v.w;
    }
#pragma unroll
    for (int off = 32; off > 0; off >>= 1) {
        s  += __shfl_down(s, off, 64);
        ss += __shfl_down(ss, off, 64);
    }
    __shared__ float red[8];
    int wave = t >> 6, lane = t & 63;
    if (lane == 0) { red[wave * 2] = s; red[wave * 2 + 1] = ss; }
    __syncthreads();
    if (t == 0) {
        float S  = red[0] + red[2] + red[4] + red[6];
        float SS = red[1] + red[3] + red[5] + red[7];
        atomicAdd(&stats[(which * 64 + c) * 16],     S);
        atomicAdd(&stats[(which * 64 + c) * 16 + 4], SS);
    }
}

// ---------------------------------------------------------------------------
// Kernel 3: KV partials (atomic-free into d_out scratch) + vsum (padded
// atomics). kn = L2-normalized-over-c BN(Yk). UNCHANGED (control).
// grid (64 chunks, 8 batch), block 256.
// ---------------------------------------------------------------------------
__global__ __launch_bounds__(256) void kv_kernel(
    const float* __restrict__ Yk, const float* __restrict__ Vv,
    const float* __restrict__ stats, const float* __restrict__ gamma,
    const float* __restrict__ beta, float* __restrict__ KVp,
    float* __restrict__ vsum)
{
    const int chunk = blockIdx.x;       // 0..63, 64 cols
    const int b     = blockIdx.y;
    __shared__ float sk[64][68];
    __shared__ float sv[64][68];
    __shared__ float pn[4][64];         // per-wave norm partials
    __shared__ float rn[64];
    __shared__ float sscl[64], sshf[64];

    const int t = threadIdx.x;
    const int wave = t >> 6, lane = t & 63;
    if (t < 64) {
        float S  = stats[(64 + t) * 16];      // which = 1 (k)
        float SS = stats[(64 + t) * 16 + 4];
        float mean = S * (1.f / BN_COUNT);
        float var  = SS * (1.f / BN_COUNT) - mean * mean;
        float scl  = gamma[t] * rsqrtf(var + 1e-5f);
        sscl[t] = scl;
        sshf[t] = beta[t] - mean * scl;
    }
    __syncthreads();

    const int n0 = chunk * 64;
    const float* Ykb = Yk + (size_t)b * (CK * NTOT) + n0;
    const float* Vb  = Vv + (size_t)b * (CK * NTOT) + n0;

#pragma unroll
    for (int r = 0; r < 4; ++r) {
        int idx4 = t + r * 256;           // 0..1023
        int c  = idx4 >> 4;               // 0..63
        int j4 = (idx4 & 15) << 2;        // 0..60
        float4 kf = *(const float4*)(Ykb + (size_t)c * NTOT + j4);
        float4 vf = *(const float4*)(Vb  + (size_t)c * NTOT + j4);
        float scl = sscl[c], sh = sshf[c];
        float4 ks = make_float4(kf.x * scl + sh, kf.y * scl + sh,
                                kf.z * scl + sh, kf.w * scl + sh);
        *(float4*)&sk[c][j4] = ks;
        *(float4*)&sv[c][j4] = vf;
    }
    __syncthreads();

    // Parallel norm partials: wave w sums channels w*16..+16 for its lane-col
    {
        float s = 0.f;
#pragma unroll
        for (int i = 0; i < 16; ++i) { float x = sk[wave * 16 + i][lane]; s += x * x; }
        pn[wave][lane] = s;
    }
    // vsum partials: thread t covers channel t>>2, column quarter t&3
    {
        const int v = t >> 2, q = t & 3;
        float s = 0.f;
#pragma unroll
        for (int i = 0; i < 16; ++i) s += sv[v][q * 16 + i];
        s += __shfl_down(s, 2, 64);
        s += __shfl_down(s, 1, 64);
        if (q == 0) atomicAdd(&vsum[((size_t)b * 64 + v) * 16], s);
    }
    __syncthreads();
    if (t < 64)
        rn[t] = 1.f / (sqrtf(pn[0][t] + pn[1][t] + pn[2][t] + pn[3][t]) + 1e-7f);
    __syncthreads();

    // GEMM: acc[c4][v4] over 64 columns, rn folded into the A-operand
    const int tc = t >> 4, tv = t & 15;
    float acc[4][4];
#pragma unroll
    for (int i = 0; i < 4; ++i)
#pragma unroll
        for (int k2 = 0; k2 < 4; ++k2) acc[i][k2] = 0.f;

#pragma unroll 2
    for (int jq = 0; jq < 16; ++jq) {
        float4 rq = *(const float4*)&rn[jq * 4];
        float4 a4[4], b4[4];
#pragma unroll
        for (int i = 0; i < 4; ++i) {
            float4 k4 = *(const float4*)&sk[tc * 4 + i][jq * 4];
            a4[i] = make_float4(k4.x * rq.x, k4.y * rq.y, k4.z * rq.z, k4.w * rq.w);
        }
#pragma unroll
        for (int k2 = 0; k2 < 4; ++k2) b4[k2] = *(const float4*)&sv[tv * 4 + k2][jq * 4];
#pragma unroll
        for (int i = 0; i < 4; ++i)
#pragma unroll
            for (int k2 = 0; k2 < 4; ++k2) {
                acc[i][k2] += a4[i].x * b4[k2].x + a4[i].y * b4[k2].y
                            + a4[i].z * b4[k2].z + a4[i].w * b4[k2].w;
            }
    }

    // Deterministic, coalesced partial store: KVp[b][chunk][c][v]
    float* P = KVp + ((size_t)(b * 64 + chunk)) * 4096;
#pragma unroll
    for (int i = 0; i < 4; ++i) {
        float4 st = make_float4(acc[i][0], acc[i][1], acc[i][2], acc[i][3]);
        *(float4*)&P[(tc * 4 + i) * 64 + tv * 4] = st;
    }
}

// ---------------------------------------------------------------------------
// Kernel 4: fused reduce+GEMM (round-7 structure, proven). grid (16, 8).
// ---------------------------------------------------------------------------
__global__ __launch_bounds__(256) void m_kernel(
    const float* __restrict__ KVp, const float* __restrict__ vsum,
    const float* __restrict__ Ww, const float* __restrict__ bw,
    float* __restrict__ M, float* __restrict__ d)
{
    const int slice = blockIdx.x;       // 0..15 -> c rows slice*4..+4
    const int b     = blockIdx.y;
    __shared__ float part[256][4];      // per-thread float4 partials
    __shared__ float sKV[4][68];        // reduced slice rows
    __shared__ float sWw[128][68];      // full Ww, padded rows
    __shared__ float svs[64];
    const int t = threadIdx.x;

    // Stage full Ww: 128 o x 64 v = 2048 float4s, 8 per thread
#pragma unroll
    for (int r = 0; r < 8; ++r) {
        int idx4 = t + r * 256;          // 0..2047
        int o  = idx4 >> 4;              // 0..127
        int v4 = (idx4 & 15) << 2;       // 0..60
        *(float4*)&sWw[o][v4] = *(const float4*)(Ww + (size_t)o * 64 + v4);
    }
    if (t < 64) svs[t] = vsum[((size_t)b * 64 + t) * 16];

    // Reduce KVp over 64 chunks for this 4-row slice
    const int chl = t >> 6;              // 0..3
    const int ci  = (t >> 4) & 3;        // 0..3  (c within slice)
    const int v4  = (t & 15) << 2;       // 0..60
    const size_t rowoff = ((size_t)(slice * 4 + ci)) * 64 + v4;
    float4 a4 = make_float4(0.f, 0.f, 0.f, 0.f);
#pragma unroll 4
    for (int it = 0; it < 16; ++it) {
        int ch = it * 4 + chl;
        float4 x = *(const float4*)(KVp + ((size_t)(b * 64 + ch)) * 4096 + rowoff);
        a4.x += x.x; a4.y += x.y; a4.z += x.z; a4.w += x.w;
    }
    *(float4*)&part[t][0] = a4;
    __syncthreads();
    if (t < 64) {
        float4 p0 = *(const float4*)&part[t][0];
        float4 p1 = *(const float4*)&part[t + 64][0];
        float4 p2 = *(const float4*)&part[t + 128][0];
        float4 p3 = *(const float4*)&part[t + 192][0];
        *(float4*)&sKV[(t >> 4) & 3][(t & 15) << 2] =
            make_float4(p0.x + p1.x + p2.x + p3.x, p0.y + p1.y + p2.y + p3.y,
                        p0.z + p1.z + p2.z + p3.z, p0.w + p1.w + p2.w + p3.w);
    }
    __syncthreads();

    // GEMM: 4 c x 128 o = 512 outputs, 2 per thread
    float* Mb = M + (size_t)b * (CK * CO);
#pragma unroll
    for (int rep = 0; rep < 2; ++rep) {
        int idx = t + rep * 256;         // 0..511
        int c = idx >> 7, o = idx & 127;
        float acc = 0.f;
#pragma unroll
        for (int vq = 0; vq < 16; ++vq) {
            float4 kv4 = *(const float4*)&sKV[c][vq * 4];
            float4 w4  = *(const float4*)&sWw[o][vq * 4];
            acc += kv4.x * w4.x + kv4.y * w4.y + kv4.z * w4.z + kv4.w * w4.w;
        }
        Mb[(size_t)(slice * 4 + c) * CO + o] = acc;
    }

    // d: only slice-0 blocks
    if (slice == 0 && t < 128) {
        float acc = bw[t];
#pragma unroll 16
        for (int v = 0; v < 64; ++v) acc += sWw[t][v] * svs[v];
        d[(size_t)b * CO + t] = acc;
    }
}

// ---------------------------------------------------------------------------
// Kernel 5: out[b,o,n] = d[b,o] + rn[n] * sum_c sq[b,c,n] * M[b,c,o].
// Round-7 structure (32-col chunks), unchanged (control). grid (128, 8).
// ---------------------------------------------------------------------------
__global__ __launch_bounds__(256) void out_kernel(
    const float* __restrict__ Yq, const float* __restrict__ stats,
    const float* __restrict__ gamma, const float* __restrict__ beta,
    const float* __restrict__ M, const float* __restrict__ d,
    float* __restrict__ out)
{
    const int chunk = blockIdx.x;    // 0..127, 32 cols
    const int b     = blockIdx.y;
    __shared__ float sM[CK * CO];    // [c][o] flat, 32 KB
    __shared__ float sq[64][36];     // 32 cols + pad
    __shared__ float pn[8][32];
    __shared__ float rn[32];
    __shared__ float sd[CO];
    __shared__ float sscl[64], sshf[64];

    const int t = threadIdx.x;
    const int n0 = chunk * 32;

#pragma unroll
    for (int r = 0; r < 8; ++r) {
        int idx4 = t + r * 256;
        ((float4*)sM)[idx4] = ((const float4*)(M + (size_t)b * (CK * CO)))[idx4];
    }
    if (t < CO) sd[t] = d[(size_t)b * CO + t];
    if (t < 64) {
        float S  = stats[t * 16];            // which = 0 (q)
        float SS = stats[t * 16 + 4];
        float mean = S * (1.f / BN_COUNT);
        float var  = SS * (1.f / BN_COUNT) - mean * mean;
        float scl  = gamma[t] * rsqrtf(var + 1e-5f);
        sscl[t] = scl;
        sshf[t] = beta[t] - mean * scl;
    }
    __syncthreads();   // sscl/sshf ready before sq staging

    const float* Yb = Yq + (size_t)b * (CK * NTOT) + n0;
#pragma unroll
    for (int r = 0; r < 2; ++r) {
        int idx4 = t + r * 256;        // 0..511
        int c  = idx4 >> 3;            // 0..63
        int j4 = (idx4 & 7) << 2;      // 0..28
        float4 xv = *(const float4*)(Yb + (size_t)c * NTOT + j4);
        float scl = sscl[c], sh = sshf[c];
        sq[c][j4 + 0] = xv.x * scl + sh;
        sq[c][j4 + 1] = xv.y * scl + sh;
        sq[c][j4 + 2] = xv.z * scl + sh;
        sq[c][j4 + 3] = xv.w * scl + sh;
    }
    __syncthreads();

    // Parallel norm partials: group g (of 8) sums channels g*8..+8 per col
    {
        const int col = t & 31, g = t >> 5;
        float s = 0.f;
#pragma unroll
        for (int i = 0; i < 8; ++i) { float x = sq[g * 8 + i][col]; s += x * x; }
        pn[g][col] = s;
    }
    __syncthreads();
    if (t < 32) {
        float s2 = pn[0][t] + pn[1][t] + pn[2][t] + pn[3][t]
                 + pn[4][t] + pn[5][t] + pn[6][t] + pn[7][t];
        rn[t] = 1.f / (sqrtf(s2) + 1e-7f);
    }
    __syncthreads();

    const int j0 = (t & 7) << 2;        // 4 columns
    const int o0 = (t >> 3) << 2;       // 4 out-channels
    float acc[4][4];
#pragma unroll
    for (int jj = 0; jj < 4; ++jj)
#pragma unroll
        for (int oo = 0; oo < 4; ++oo) acc[jj][oo] = 0.f;

#pragma unroll 4
    for (int c = 0; c < 64; ++c) {
        float4 qv = *(const float4*)&sq[c][j0];
        float4 m0 = *(const float4*)&sM[c * CO + o0];
        float aq[4] = {qv.x, qv.y, qv.z, qv.w};
        float am[4] = {m0.x, m0.y, m0.z, m0.w};
#pragma unroll
        for (int jj = 0; jj < 4; ++jj)
#pragma unroll
            for (int oo = 0; oo < 4; ++oo) acc[jj][oo] += aq[jj] * am[oo];
    }

    float4 rq = *(const float4*)&rn[j0];   // per-thread column norms

    float* outb = out + (size_t)b * (CO * NTOT) + n0;
#pragma unroll
    for (int oo = 0; oo < 4; ++oo) {
        float dd = sd[o0 + oo];
        float4 st = make_float4(acc[0][oo] * rq.x + dd,
                                acc[1][oo] * rq.y + dd,
                                acc[2][oo] * rq.z + dd,
                                acc[3][oo] * rq.w + dd);
        *(float4*)&outb[(size_t)(o0 + oo) * NTOT + j0] = st;
    }
}

// ---------------------------------------------------------------------------
extern "C" void kernel_launch(void* const* d_in, const int* in_sizes, int n_in,
                              void* d_out, int out_size, void* d_ws, size_t ws_size,
                              hipStream_t stream) {
    (void)in_sizes; (void)n_in; (void)out_size; (void)ws_size;
    const float* q     = (const float*)d_in[0];
    const float* k     = (const float*)d_in[1];
    const float* v     = (const float*)d_in[2];
    const float* Wk    = (const float*)d_in[3];
    const float* bk    = (const float*)d_in[4];
    const float* gamma = (const float*)d_in[5];
    const float* beta  = (const float*)d_in[6];
    const float* Wv    = (const float*)d_in[7];
    const float* bv    = (const float*)d_in[8];
    const float* Ww    = (const float*)d_in[9];
    const float* bw    = (const float*)d_in[10];
    float* out = (float*)d_out;
    float* ws  = (float*)d_ws;

    float* Yq    = ws + OFF_YQ;
    float* Yk    = ws + OFF_YK;
    float* Vv    = ws + OFF_V;
    float* stats = ws + OFF_STATS;
    float* vsum  = ws + OFF_VSUM;
    float* M     = ws + OFF_M;     // aliases dead Yk region (stream-ordered safe)
    float* dd    = ws + OFF_D;     // aliases dead Yk region
    float* KVp   = out;            // d_out as scratch; fully overwritten by out_kernel

    // zero atomic-accumulated buffers (stats + vsum contiguous, 40 KB)
    hipMemsetAsync(stats, 0, (2048 + 8192) * sizeof(float), stream);

    gemm3_kernel<<<dim3(64, NBATCH, 3), 256, 0, stream>>>(
        q, k, v, Wk, bk, Wv, bv, Yq, Yk, Vv);
    stats_kernel<<<dim3(8, 64, 2), 256, 0, stream>>>(Yq, Yk, stats);
    kv_kernel<<<dim3(64, NBATCH), 256, 0, stream>>>(Yk, Vv, stats, gamma, beta, KVp, vsum);
    m_kernel<<<dim3(16, NBATCH), 256, 0, stream>>>(KVp, vsum, Ww, bw, M, dd);
    out_kernel<<<dim3(128, NBATCH), 256, 0, stream>>>(Yq, stats, gamma, beta, M, dd, out);
}

// Round 9
// 198.500 us; speedup vs baseline: 1.0354x; 1.0354x over previous
//
#include <hip/hip_runtime.h>
#include <math.h>

// Problem constants
#define NTOT 4096        // H*W = 64*64
#define NBATCH 8
#define CIN 128
#define CK 64
#define CV 64
#define CO 128
#define BN_COUNT 32768.0f // B*H*W

// Workspace layout (float offsets).
// stats: [(which*64+c)*16] sum, +4 sumsq  (line-exclusive per channel)
// vsum : [(b*64+v)*16]                    (line-exclusive per (b,v))
// M,d  : aliased into dead Yk region (Yk last read by kv_kernel; m_kernel after)
// KVp  : 64-chunk partials of KV in d_out scratch (overwritten by out_kernel)
#define OFF_YQ    0ul
#define OFF_YK    2097152ul
#define OFF_V     4194304ul
#define OFF_STATS 6291456ul           // 2*64*16 = 2048 floats
#define OFF_VSUM  6293504ul           // 8*64*16 = 8192 floats
#define OFF_M     2097152ul           // = OFF_YK, [b][64][128] = 65536 floats
#define OFF_D     2162688ul           // [b][128] = 1024 floats

// ---------------------------------------------------------------------------
// Kernel 1: LDS-staged 1x1-conv GEMM, round-7 proven body (16 independent
// acc chains = full FMA-latency hiding; round-8's 2-chain variant regressed
// 56->90us). Split into one dispatch per tensor (q,k,v) so the profiler's
// top-5 reveals kv/out/stats durations. grid (64 col-chunks, 8 batch).
// ---------------------------------------------------------------------------
__global__ __launch_bounds__(256) void gemm_kernel(
    const float* __restrict__ X, const float* __restrict__ W,
    const float* __restrict__ bias, float* __restrict__ Y)
{
    const int chunk = blockIdx.x;
    const int b     = blockIdx.y;

    __shared__ float sX[CIN][64];   // 32 KB

    const int t = threadIdx.x;
    const int lane = t & 63;
    const int wu = __builtin_amdgcn_readfirstlane(t >> 6);  // wave id, uniform

    const int n0 = chunk * 64;
    const float* Xb = X + (size_t)b * (CIN * NTOT) + n0;

#pragma unroll
    for (int r = 0; r < 8; ++r) {
        int idx4 = t + r * 256;           // 0..2047
        int c  = idx4 >> 4;               // 0..127
        int j4 = (idx4 & 15) << 2;        // 0..60
        float4 xv = *(const float4*)(Xb + (size_t)c * NTOT + j4);
        *(float4*)&sX[c][j4] = xv;
    }
    __syncthreads();

    const float* Wp = W + (size_t)wu * 16 * CIN;
    float acc[16];
#pragma unroll
    for (int ki = 0; ki < 16; ++ki) acc[ki] = 0.f;

#pragma unroll 8
    for (int c = 0; c < CIN; ++c) {
        float xv = sX[c][lane];
#pragma unroll
        for (int ki = 0; ki < 16; ++ki)
            acc[ki] += xv * Wp[ki * CIN + c];   // wave-uniform -> s_load
    }

    float* Yb = Y + (size_t)b * (CK * NTOT) + n0;
#pragma unroll
    for (int ki = 0; ki < 16; ++ki) {
        int o = wu * 16 + ki;
        Yb[(size_t)o * NTOT + lane] = acc[ki] + bias[o];
    }
}

// ---------------------------------------------------------------------------
// Kernel 2: BN batch stats. grid (8 n-splits, 64 c, 2 tensors) = 1024 blocks;
// 16KB coalesced per block, block-reduce, 2 padded atomics (16 ops/line).
// ---------------------------------------------------------------------------
__global__ __launch_bounds__(256) void stats_kernel(
    const float* __restrict__ Yq, const float* __restrict__ Yk,
    float* __restrict__ stats)
{
    const int nsplit = blockIdx.x;   // 0..7
    const int c      = blockIdx.y;   // 0..63
    const int which  = blockIdx.z;   // 0..1
    const float* Y = which ? Yk : Yq;
    const int t = threadIdx.x;

    float s = 0.f, ss = 0.f;
#pragma unroll
    for (int p = 0; p < 4; ++p) {
        int b = (t >> 7) + p * 2;        // 2 batches per pass
        int e = (t & 127) << 2;          // 0..508
        const float* src = Y + (size_t)b * (CK * NTOT) + (size_t)c * NTOT
                         + nsplit * 512 + e;
        float4 v = *(const float4*)src;
        s  += v.x + v.y + v.z + v.w;
        ss += v.x * v.x + v.y * v.y + v.z * v.z + v.w * v.w;
    }
#pragma unroll
    for (int off = 32; off > 0; off >>= 1) {
        s  += __shfl_down(s, off, 64);
        ss += __shfl_down(ss, off, 64);
    }
    __shared__ float red[8];
    int wave = t >> 6, lane = t & 63;
    if (lane == 0) { red[wave * 2] = s; red[wave * 2 + 1] = ss; }
    __syncthreads();
    if (t == 0) {
        float S  = red[0] + red[2] + red[4] + red[6];
        float SS = red[1] + red[3] + red[5] + red[7];
        atomicAdd(&stats[(which * 64 + c) * 16],     S);
        atomicAdd(&stats[(which * 64 + c) * 16 + 4], SS);
    }
}

// ---------------------------------------------------------------------------
// Kernel 3: KV partials (atomic-free into d_out scratch) + vsum (padded
// atomics). kn = L2-normalized-over-c BN(Yk). UNCHANGED (control).
// grid (64 chunks, 8 batch), block 256.
// ---------------------------------------------------------------------------
__global__ __launch_bounds__(256) void kv_kernel(
    const float* __restrict__ Yk, const float* __restrict__ Vv,
    const float* __restrict__ stats, const float* __restrict__ gamma,
    const float* __restrict__ beta, float* __restrict__ KVp,
    float* __restrict__ vsum)
{
    const int chunk = blockIdx.x;       // 0..63, 64 cols
    const int b     = blockIdx.y;
    __shared__ float sk[64][68];
    __shared__ float sv[64][68];
    __shared__ float pn[4][64];         // per-wave norm partials
    __shared__ float rn[64];
    __shared__ float sscl[64], sshf[64];

    const int t = threadIdx.x;
    const int wave = t >> 6, lane = t & 63;
    if (t < 64) {
        float S  = stats[(64 + t) * 16];      // which = 1 (k)
        float SS = stats[(64 + t) * 16 + 4];
        float mean = S * (1.f / BN_COUNT);
        float var  = SS * (1.f / BN_COUNT) - mean * mean;
        float scl  = gamma[t] * rsqrtf(var + 1e-5f);
        sscl[t] = scl;
        sshf[t] = beta[t] - mean * scl;
    }
    __syncthreads();

    const int n0 = chunk * 64;
    const float* Ykb = Yk + (size_t)b * (CK * NTOT) + n0;
    const float* Vb  = Vv + (size_t)b * (CK * NTOT) + n0;

#pragma unroll
    for (int r = 0; r < 4; ++r) {
        int idx4 = t + r * 256;           // 0..1023
        int c  = idx4 >> 4;               // 0..63
        int j4 = (idx4 & 15) << 2;        // 0..60
        float4 kf = *(const float4*)(Ykb + (size_t)c * NTOT + j4);
        float4 vf = *(const float4*)(Vb  + (size_t)c * NTOT + j4);
        float scl = sscl[c], sh = sshf[c];
        float4 ks = make_float4(kf.x * scl + sh, kf.y * scl + sh,
                                kf.z * scl + sh, kf.w * scl + sh);
        *(float4*)&sk[c][j4] = ks;
        *(float4*)&sv[c][j4] = vf;
    }
    __syncthreads();

    // Parallel norm partials: wave w sums channels w*16..+16 for its lane-col
    {
        float s = 0.f;
#pragma unroll
        for (int i = 0; i < 16; ++i) { float x = sk[wave * 16 + i][lane]; s += x * x; }
        pn[wave][lane] = s;
    }
    // vsum partials: thread t covers channel t>>2, column quarter t&3
    {
        const int v = t >> 2, q = t & 3;
        float s = 0.f;
#pragma unroll
        for (int i = 0; i < 16; ++i) s += sv[v][q * 16 + i];
        s += __shfl_down(s, 2, 64);
        s += __shfl_down(s, 1, 64);
        if (q == 0) atomicAdd(&vsum[((size_t)b * 64 + v) * 16], s);
    }
    __syncthreads();
    if (t < 64)
        rn[t] = 1.f / (sqrtf(pn[0][t] + pn[1][t] + pn[2][t] + pn[3][t]) + 1e-7f);
    __syncthreads();

    // GEMM: acc[c4][v4] over 64 columns, rn folded into the A-operand
    const int tc = t >> 4, tv = t & 15;
    float acc[4][4];
#pragma unroll
    for (int i = 0; i < 4; ++i)
#pragma unroll
        for (int k2 = 0; k2 < 4; ++k2) acc[i][k2] = 0.f;

#pragma unroll 2
    for (int jq = 0; jq < 16; ++jq) {
        float4 rq = *(const float4*)&rn[jq * 4];
        float4 a4[4], b4[4];
#pragma unroll
        for (int i = 0; i < 4; ++i) {
            float4 k4 = *(const float4*)&sk[tc * 4 + i][jq * 4];
            a4[i] = make_float4(k4.x * rq.x, k4.y * rq.y, k4.z * rq.z, k4.w * rq.w);
        }
#pragma unroll
        for (int k2 = 0; k2 < 4; ++k2) b4[k2] = *(const float4*)&sv[tv * 4 + k2][jq * 4];
#pragma unroll
        for (int i = 0; i < 4; ++i)
#pragma unroll
            for (int k2 = 0; k2 < 4; ++k2) {
                acc[i][k2] += a4[i].x * b4[k2].x + a4[i].y * b4[k2].y
                            + a4[i].z * b4[k2].z + a4[i].w * b4[k2].w;
            }
    }

    // Deterministic, coalesced partial store: KVp[b][chunk][c][v]
    float* P = KVp + ((size_t)(b * 64 + chunk)) * 4096;
#pragma unroll
    for (int i = 0; i < 4; ++i) {
        float4 st = make_float4(acc[i][0], acc[i][1], acc[i][2], acc[i][3]);
        *(float4*)&P[(tc * 4 + i) * 64 + tv * 4] = st;
    }
}

// ---------------------------------------------------------------------------
// Kernel 4: fused reduce+GEMM (round-7 structure, proven). grid (16, 8).
// ---------------------------------------------------------------------------
__global__ __launch_bounds__(256) void m_kernel(
    const float* __restrict__ KVp, const float* __restrict__ vsum,
    const float* __restrict__ Ww, const float* __restrict__ bw,
    float* __restrict__ M, float* __restrict__ d)
{
    const int slice = blockIdx.x;       // 0..15 -> c rows slice*4..+4
    const int b     = blockIdx.y;
    __shared__ float part[256][4];      // per-thread float4 partials
    __shared__ float sKV[4][68];        // reduced slice rows
    __shared__ float sWw[128][68];      // full Ww, padded rows
    __shared__ float svs[64];
    const int t = threadIdx.x;

    // Stage full Ww: 128 o x 64 v = 2048 float4s, 8 per thread
#pragma unroll
    for (int r = 0; r < 8; ++r) {
        int idx4 = t + r * 256;          // 0..2047
        int o  = idx4 >> 4;              // 0..127
        int v4 = (idx4 & 15) << 2;       // 0..60
        *(float4*)&sWw[o][v4] = *(const float4*)(Ww + (size_t)o * 64 + v4);
    }
    if (t < 64) svs[t] = vsum[((size_t)b * 64 + t) * 16];

    // Reduce KVp over 64 chunks for this 4-row slice
    const int chl = t >> 6;              // 0..3
    const int ci  = (t >> 4) & 3;        // 0..3  (c within slice)
    const int v4  = (t & 15) << 2;       // 0..60
    const size_t rowoff = ((size_t)(slice * 4 + ci)) * 64 + v4;
    float4 a4 = make_float4(0.f, 0.f, 0.f, 0.f);
#pragma unroll 4
    for (int it = 0; it < 16; ++it) {
        int ch = it * 4 + chl;
        float4 x = *(const float4*)(KVp + ((size_t)(b * 64 + ch)) * 4096 + rowoff);
        a4.x += x.x; a4.y += x.y; a4.z += x.z; a4.w += x.w;
    }
    *(float4*)&part[t][0] = a4;
    __syncthreads();
    if (t < 64) {
        float4 p0 = *(const float4*)&part[t][0];
        float4 p1 = *(const float4*)&part[t + 64][0];
        float4 p2 = *(const float4*)&part[t + 128][0];
        float4 p3 = *(const float4*)&part[t + 192][0];
        *(float4*)&sKV[(t >> 4) & 3][(t & 15) << 2] =
            make_float4(p0.x + p1.x + p2.x + p3.x, p0.y + p1.y + p2.y + p3.y,
                        p0.z + p1.z + p2.z + p3.z, p0.w + p1.w + p2.w + p3.w);
    }
    __syncthreads();

    // GEMM: 4 c x 128 o = 512 outputs, 2 per thread
    float* Mb = M + (size_t)b * (CK * CO);
#pragma unroll
    for (int rep = 0; rep < 2; ++rep) {
        int idx = t + rep * 256;         // 0..511
        int c = idx >> 7, o = idx & 127;
        float acc = 0.f;
#pragma unroll
        for (int vq = 0; vq < 16; ++vq) {
            float4 kv4 = *(const float4*)&sKV[c][vq * 4];
            float4 w4  = *(const float4*)&sWw[o][vq * 4];
            acc += kv4.x * w4.x + kv4.y * w4.y + kv4.z * w4.z + kv4.w * w4.w;
        }
        Mb[(size_t)(slice * 4 + c) * CO + o] = acc;
    }

    // d: only slice-0 blocks
    if (slice == 0 && t < 128) {
        float acc = bw[t];
#pragma unroll 16
        for (int v = 0; v < 64; ++v) acc += sWw[t][v] * svs[v];
        d[(size_t)b * CO + t] = acc;
    }
}

// ---------------------------------------------------------------------------
// Kernel 5: out[b,o,n] = d[b,o] + rn[n] * sum_c sq[b,c,n] * M[b,c,o].
// Round-7 structure (32-col chunks), unchanged (control). grid (128, 8).
// ---------------------------------------------------------------------------
__global__ __launch_bounds__(256) void out_kernel(
    const float* __restrict__ Yq, const float* __restrict__ stats,
    const float* __restrict__ gamma, const float* __restrict__ beta,
    const float* __restrict__ M, const float* __restrict__ d,
    float* __restrict__ out)
{
    const int chunk = blockIdx.x;    // 0..127, 32 cols
    const int b     = blockIdx.y;
    __shared__ float sM[CK * CO];    // [c][o] flat, 32 KB
    __shared__ float sq[64][36];     // 32 cols + pad
    __shared__ float pn[8][32];
    __shared__ float rn[32];
    __shared__ float sd[CO];
    __shared__ float sscl[64], sshf[64];

    const int t = threadIdx.x;
    const int n0 = chunk * 32;

#pragma unroll
    for (int r = 0; r < 8; ++r) {
        int idx4 = t + r * 256;
        ((float4*)sM)[idx4] = ((const float4*)(M + (size_t)b * (CK * CO)))[idx4];
    }
    if (t < CO) sd[t] = d[(size_t)b * CO + t];
    if (t < 64) {
        float S  = stats[t * 16];            // which = 0 (q)
        float SS = stats[t * 16 + 4];
        float mean = S * (1.f / BN_COUNT);
        float var  = SS * (1.f / BN_COUNT) - mean * mean;
        float scl  = gamma[t] * rsqrtf(var + 1e-5f);
        sscl[t] = scl;
        sshf[t] = beta[t] - mean * scl;
    }
    __syncthreads();   // sscl/sshf ready before sq staging

    const float* Yb = Yq + (size_t)b * (CK * NTOT) + n0;
#pragma unroll
    for (int r = 0; r < 2; ++r) {
        int idx4 = t + r * 256;        // 0..511
        int c  = idx4 >> 3;            // 0..63
        int j4 = (idx4 & 7) << 2;      // 0..28
        float4 xv = *(const float4*)(Yb + (size_t)c * NTOT + j4);
        float scl = sscl[c], sh = sshf[c];
        sq[c][j4 + 0] = xv.x * scl + sh;
        sq[c][j4 + 1] = xv.y * scl + sh;
        sq[c][j4 + 2] = xv.z * scl + sh;
        sq[c][j4 + 3] = xv.w * scl + sh;
    }
    __syncthreads();

    // Parallel norm partials: group g (of 8) sums channels g*8..+8 per col
    {
        const int col = t & 31, g = t >> 5;
        float s = 0.f;
#pragma unroll
        for (int i = 0; i < 8; ++i) { float x = sq[g * 8 + i][col]; s += x * x; }
        pn[g][col] = s;
    }
    __syncthreads();
    if (t < 32) {
        float s2 = pn[0][t] + pn[1][t] + pn[2][t] + pn[3][t]
                 + pn[4][t] + pn[5][t] + pn[6][t] + pn[7][t];
        rn[t] = 1.f / (sqrtf(s2) + 1e-7f);
    }
    __syncthreads();

    const int j0 = (t & 7) << 2;        // 4 columns
    const int o0 = (t >> 3) << 2;       // 4 out-channels
    float acc[4][4];
#pragma unroll
    for (int jj = 0; jj < 4; ++jj)
#pragma unroll
        for (int oo = 0; oo < 4; ++oo) acc[jj][oo] = 0.f;

#pragma unroll 4
    for (int c = 0; c < 64; ++c) {
        float4 qv = *(const float4*)&sq[c][j0];
        float4 m0 = *(const float4*)&sM[c * CO + o0];
        float aq[4] = {qv.x, qv.y, qv.z, qv.w};
        float am[4] = {m0.x, m0.y, m0.z, m0.w};
#pragma unroll
        for (int jj = 0; jj < 4; ++jj)
#pragma unroll
            for (int oo = 0; oo < 4; ++oo) acc[jj][oo] += aq[jj] * am[oo];
    }

    float4 rq = *(const float4*)&rn[j0];   // per-thread column norms

    float* outb = out + (size_t)b * (CO * NTOT) + n0;
#pragma unroll
    for (int oo = 0; oo < 4; ++oo) {
        float dd = sd[o0 + oo];
        float4 st = make_float4(acc[0][oo] * rq.x + dd,
                                acc[1][oo] * rq.y + dd,
                                acc[2][oo] * rq.z + dd,
                                acc[3][oo] * rq.w + dd);
        *(float4*)&outb[(size_t)(o0 + oo) * NTOT + j0] = st;
    }
}

// ---------------------------------------------------------------------------
extern "C" void kernel_launch(void* const* d_in, const int* in_sizes, int n_in,
                              void* d_out, int out_size, void* d_ws, size_t ws_size,
                              hipStream_t stream) {
    (void)in_sizes; (void)n_in; (void)out_size; (void)ws_size;
    const float* q     = (const float*)d_in[0];
    const float* k     = (const float*)d_in[1];
    const float* v     = (const float*)d_in[2];
    const float* Wk    = (const float*)d_in[3];
    const float* bk    = (const float*)d_in[4];
    const float* gamma = (const float*)d_in[5];
    const float* beta  = (const float*)d_in[6];
    const float* Wv    = (const float*)d_in[7];
    const float* bv    = (const float*)d_in[8];
    const float* Ww    = (const float*)d_in[9];
    const float* bw    = (const float*)d_in[10];
    float* out = (float*)d_out;
    float* ws  = (float*)d_ws;

    float* Yq    = ws + OFF_YQ;
    float* Yk    = ws + OFF_YK;
    float* Vv    = ws + OFF_V;
    float* stats = ws + OFF_STATS;
    float* vsum  = ws + OFF_VSUM;
    float* M     = ws + OFF_M;     // aliases dead Yk region (stream-ordered safe)
    float* dd    = ws + OFF_D;     // aliases dead Yk region
    float* KVp   = out;            // d_out as scratch; fully overwritten by out_kernel

    // zero atomic-accumulated buffers (stats + vsum contiguous, 40 KB)
    hipMemsetAsync(stats, 0, (2048 + 8192) * sizeof(float), stream);

    gemm_kernel<<<dim3(64, NBATCH), 256, 0, stream>>>(q, Wk, bk, Yq);
    gemm_kernel<<<dim3(64, NBATCH), 256, 0, stream>>>(k, Wk, bk, Yk);
    gemm_kernel<<<dim3(64, NBATCH), 256, 0, stream>>>(v, Wv, bv, Vv);
    stats_kernel<<<dim3(8, 64, 2), 256, 0, stream>>>(Yq, Yk, stats);
    kv_kernel<<<dim3(64, NBATCH), 256, 0, stream>>>(Yk, Vv, stats, gamma, beta, KVp, vsum);
    m_kernel<<<dim3(16, NBATCH), 256, 0, stream>>>(KVp, vsum, Ww, bw, M, dd);
    out_kernel<<<dim3(128, NBATCH), 256, 0, stream>>>(Yq, stats, gamma, beta, M, dd, out);
}

// Round 10
// 182.720 us; speedup vs baseline: 1.1248x; 1.0864x over previous
//
#include <hip/hip_runtime.h>
#include <math.h>

// Problem constants
#define NTOT 4096        // H*W = 64*64
#define NBATCH 8
#define CIN 128
#define CK 64
#define CV 64
#define CO 128
#define BN_COUNT 32768.0f // B*H*W

// Workspace layout (float offsets).
// statsP: [(which*64+c)*16 + ns] sum partial (ns=0..7), +8+ns sumsq partial.
//         DETERMINISTIC (each stats block owns one slot) -> no memset needed.
// M,d   : aliased into dead Yk region (Yk last read by kv_kernel; m after)
// KVp   : [b][chunk][c][v] partials in d_out scratch (overwritten by out)
// vsumP : [b][chunk][v] partials in d_out scratch after KVp
#define OFF_YQ    0ul
#define OFF_YK    2097152ul
#define OFF_V     4194304ul
#define OFF_STATS 6291456ul           // 2*64*16 = 2048 floats
#define OFF_M     2097152ul           // = OFF_YK, [b][64][128] = 65536 floats
#define OFF_D     2162688ul           // [b][128] = 1024 floats
#define KVP_FLOATS   2097152ul        // 8*64*4096
#define VSUMP_OFF    2097152ul        // (in d_out) after KVp; 8*64*64 = 32768 floats

// ---------------------------------------------------------------------------
// Kernel 1: LDS-staged 1x1-conv GEMM, round-7 proven form (z=3 combined:
// round-9 showed splitting into 3 dispatches costs ~18us of boundary drain).
// grid (64 col-chunks, 8 batch, 3 tensors), block 256.
// ---------------------------------------------------------------------------
__global__ __launch_bounds__(256) void gemm3_kernel(
    const float* __restrict__ Xq, const float* __restrict__ Xk, const float* __restrict__ Xv,
    const float* __restrict__ Wk, const float* __restrict__ bk,
    const float* __restrict__ Wv, const float* __restrict__ bv,
    float* __restrict__ Yq, float* __restrict__ Yk, float* __restrict__ Vv)
{
    const int chunk = blockIdx.x;
    const int b     = blockIdx.y;
    const int which = blockIdx.z;
    const float* X    = (which == 0) ? Xq : (which == 1) ? Xk : Xv;
    const float* W    = (which == 2) ? Wv : Wk;
    const float* bias = (which == 2) ? bv : bk;
    float* Y          = (which == 0) ? Yq : (which == 1) ? Yk : Vv;

    __shared__ float sX[CIN][64];   // 32 KB

    const int t = threadIdx.x;
    const int lane = t & 63;
    const int wu = __builtin_amdgcn_readfirstlane(t >> 6);  // wave id, uniform

    const int n0 = chunk * 64;
    const float* Xb = X + (size_t)b * (CIN * NTOT) + n0;

#pragma unroll
    for (int r = 0; r < 8; ++r) {
        int idx4 = t + r * 256;           // 0..2047
        int c  = idx4 >> 4;               // 0..127
        int j4 = (idx4 & 15) << 2;        // 0..60
        float4 xv = *(const float4*)(Xb + (size_t)c * NTOT + j4);
        *(float4*)&sX[c][j4] = xv;
    }
    __syncthreads();

    const float* Wp = W + (size_t)wu * 16 * CIN;
    float acc[16];
#pragma unroll
    for (int ki = 0; ki < 16; ++ki) acc[ki] = 0.f;

#pragma unroll 8
    for (int c = 0; c < CIN; ++c) {
        float xv = sX[c][lane];
#pragma unroll
        for (int ki = 0; ki < 16; ++ki)
            acc[ki] += xv * Wp[ki * CIN + c];   // wave-uniform -> s_load
    }

    float* Yb = Y + (size_t)b * (CK * NTOT) + n0;
#pragma unroll
    for (int ki = 0; ki < 16; ++ki) {
        int o = wu * 16 + ki;
        Yb[(size_t)o * NTOT + lane] = acc[ki] + bias[o];
    }
}

// ---------------------------------------------------------------------------
// Kernel 2: BN batch stats, DETERMINISTIC partials (no atomics, no memset).
// grid (8 n-splits, 64 c, 2 tensors) = 1024 blocks; each writes its own slot.
// ---------------------------------------------------------------------------
__global__ __launch_bounds__(256) void stats_kernel(
    const float* __restrict__ Yq, const float* __restrict__ Yk,
    float* __restrict__ statsP)
{
    const int nsplit = blockIdx.x;   // 0..7
    const int c      = blockIdx.y;   // 0..63
    const int which  = blockIdx.z;   // 0..1
    const float* Y = which ? Yk : Yq;
    const int t = threadIdx.x;

    float s = 0.f, ss = 0.f;
#pragma unroll
    for (int p = 0; p < 4; ++p) {
        int b = (t >> 7) + p * 2;        // 2 batches per pass
        int e = (t & 127) << 2;          // 0..508
        const float* src = Y + (size_t)b * (CK * NTOT) + (size_t)c * NTOT
                         + nsplit * 512 + e;
        float4 v = *(const float4*)src;
        s  += v.x + v.y + v.z + v.w;
        ss += v.x * v.x + v.y * v.y + v.z * v.z + v.w * v.w;
    }
#pragma unroll
    for (int off = 32; off > 0; off >>= 1) {
        s  += __shfl_down(s, off, 64);
        ss += __shfl_down(ss, off, 64);
    }
    __shared__ float red[8];
    int wave = t >> 6, lane = t & 63;
    if (lane == 0) { red[wave * 2] = s; red[wave * 2 + 1] = ss; }
    __syncthreads();
    if (t == 0) {
        float S  = red[0] + red[2] + red[4] + red[6];
        float SS = red[1] + red[3] + red[5] + red[7];
        statsP[(which * 64 + c) * 16 + nsplit]     = S;
        statsP[(which * 64 + c) * 16 + 8 + nsplit] = SS;
    }
}

// ---------------------------------------------------------------------------
// Kernel 3: KV partials + vsum partials, all DETERMINISTIC (no atomics).
// kn = L2-normalized-over-c BN(Yk); BN scale/shift from summed stat partials.
// grid (64 chunks, 8 batch), block 256.
// ---------------------------------------------------------------------------
__global__ __launch_bounds__(256) void kv_kernel(
    const float* __restrict__ Yk, const float* __restrict__ Vv,
    const float* __restrict__ statsP, const float* __restrict__ gamma,
    const float* __restrict__ beta, float* __restrict__ KVp,
    float* __restrict__ vsumP)
{
    const int chunk = blockIdx.x;       // 0..63, 64 cols
    const int b     = blockIdx.y;
    __shared__ float sk[64][68];
    __shared__ float sv[64][68];
    __shared__ float pn[4][64];         // per-wave norm partials
    __shared__ float rn[64];
    __shared__ float sscl[64], sshf[64];

    const int t = threadIdx.x;
    const int wave = t >> 6, lane = t & 63;
    if (t < 64) {
        const float* sp = statsP + (size_t)(64 + t) * 16;   // which = 1 (k)
        float S = 0.f, SS = 0.f;
#pragma unroll
        for (int ns = 0; ns < 8; ++ns) { S += sp[ns]; SS += sp[8 + ns]; }
        float mean = S * (1.f / BN_COUNT);
        float var  = SS * (1.f / BN_COUNT) - mean * mean;
        float scl  = gamma[t] * rsqrtf(var + 1e-5f);
        sscl[t] = scl;
        sshf[t] = beta[t] - mean * scl;
    }
    __syncthreads();

    const int n0 = chunk * 64;
    const float* Ykb = Yk + (size_t)b * (CK * NTOT) + n0;
    const float* Vb  = Vv + (size_t)b * (CK * NTOT) + n0;

#pragma unroll
    for (int r = 0; r < 4; ++r) {
        int idx4 = t + r * 256;           // 0..1023
        int c  = idx4 >> 4;               // 0..63
        int j4 = (idx4 & 15) << 2;        // 0..60
        float4 kf = *(const float4*)(Ykb + (size_t)c * NTOT + j4);
        float4 vf = *(const float4*)(Vb  + (size_t)c * NTOT + j4);
        float scl = sscl[c], sh = sshf[c];
        float4 ks = make_float4(kf.x * scl + sh, kf.y * scl + sh,
                                kf.z * scl + sh, kf.w * scl + sh);
        *(float4*)&sk[c][j4] = ks;
        *(float4*)&sv[c][j4] = vf;
    }
    __syncthreads();

    // Parallel norm partials: wave w sums channels w*16..+16 for its lane-col
    {
        float s = 0.f;
#pragma unroll
        for (int i = 0; i < 16; ++i) { float x = sk[wave * 16 + i][lane]; s += x * x; }
        pn[wave][lane] = s;
    }
    // vsum partials: thread t covers channel t>>2, column quarter t&3;
    // deterministic per-(b,chunk) store (reduced later by m_kernel)
    {
        const int v = t >> 2, q = t & 3;
        float s = 0.f;
#pragma unroll
        for (int i = 0; i < 16; ++i) s += sv[v][q * 16 + i];
        s += __shfl_down(s, 2, 64);
        s += __shfl_down(s, 1, 64);
        if (q == 0) vsumP[((size_t)(b * 64 + chunk)) * 64 + v] = s;
    }
    __syncthreads();
    if (t < 64)
        rn[t] = 1.f / (sqrtf(pn[0][t] + pn[1][t] + pn[2][t] + pn[3][t]) + 1e-7f);
    __syncthreads();

    // GEMM: acc[c4][v4] over 64 columns, rn folded into the A-operand
    const int tc = t >> 4, tv = t & 15;
    float acc[4][4];
#pragma unroll
    for (int i = 0; i < 4; ++i)
#pragma unroll
        for (int k2 = 0; k2 < 4; ++k2) acc[i][k2] = 0.f;

#pragma unroll 2
    for (int jq = 0; jq < 16; ++jq) {
        float4 rq = *(const float4*)&rn[jq * 4];
        float4 a4[4], b4[4];
#pragma unroll
        for (int i = 0; i < 4; ++i) {
            float4 k4 = *(const float4*)&sk[tc * 4 + i][jq * 4];
            a4[i] = make_float4(k4.x * rq.x, k4.y * rq.y, k4.z * rq.z, k4.w * rq.w);
        }
#pragma unroll
        for (int k2 = 0; k2 < 4; ++k2) b4[k2] = *(const float4*)&sv[tv * 4 + k2][jq * 4];
#pragma unroll
        for (int i = 0; i < 4; ++i)
#pragma unroll
            for (int k2 = 0; k2 < 4; ++k2) {
                acc[i][k2] += a4[i].x * b4[k2].x + a4[i].y * b4[k2].y
                            + a4[i].z * b4[k2].z + a4[i].w * b4[k2].w;
            }
    }

    // Deterministic, coalesced partial store: KVp[b][chunk][c][v]
    float* P = KVp + ((size_t)(b * 64 + chunk)) * 4096;
#pragma unroll
    for (int i = 0; i < 4; ++i) {
        float4 st = make_float4(acc[i][0], acc[i][1], acc[i][2], acc[i][3]);
        *(float4*)&P[(tc * 4 + i) * 64 + tv * 4] = st;
    }
}

// ---------------------------------------------------------------------------
// Kernel 4: fused reduce+GEMM (round-7 structure) + vsumP reduce for d.
// grid (16 c-slices, 8 batch), block 256.
// ---------------------------------------------------------------------------
__global__ __launch_bounds__(256) void m_kernel(
    const float* __restrict__ KVp, const float* __restrict__ vsumP,
    const float* __restrict__ Ww, const float* __restrict__ bw,
    float* __restrict__ M, float* __restrict__ d)
{
    const int slice = blockIdx.x;       // 0..15 -> c rows slice*4..+4
    const int b     = blockIdx.y;
    __shared__ float part[256][4];      // per-thread float4 partials
    __shared__ float sKV[4][68];        // reduced slice rows
    __shared__ float sWw[128][68];      // full Ww, padded rows
    __shared__ float vsp[4][64];
    __shared__ float svs[64];
    const int t = threadIdx.x;

    // Stage full Ww: 128 o x 64 v = 2048 float4s, 8 per thread
#pragma unroll
    for (int r = 0; r < 8; ++r) {
        int idx4 = t + r * 256;          // 0..2047
        int o  = idx4 >> 4;              // 0..127
        int v4 = (idx4 & 15) << 2;       // 0..60
        *(float4*)&sWw[o][v4] = *(const float4*)(Ww + (size_t)o * 64 + v4);
    }

    // vsum reduce (only needed by slice 0 for d)
    if (slice == 0) {
        int prt = t >> 6;                // 0..3
        int v   = t & 63;
        float s = 0.f;
        for (int ch = prt; ch < 64; ch += 4)
            s += vsumP[((size_t)(b * 64 + ch)) * 64 + v];
        vsp[prt][v] = s;
    }

    // Reduce KVp over 64 chunks for this 4-row slice
    const int chl = t >> 6;              // 0..3
    const int ci  = (t >> 4) & 3;        // 0..3  (c within slice)
    const int v4  = (t & 15) << 2;       // 0..60
    const size_t rowoff = ((size_t)(slice * 4 + ci)) * 64 + v4;
    float4 a4 = make_float4(0.f, 0.f, 0.f, 0.f);
#pragma unroll 4
    for (int it = 0; it < 16; ++it) {
        int ch = it * 4 + chl;
        float4 x = *(const float4*)(KVp + ((size_t)(b * 64 + ch)) * 4096 + rowoff);
        a4.x += x.x; a4.y += x.y; a4.z += x.z; a4.w += x.w;
    }
    *(float4*)&part[t][0] = a4;
    __syncthreads();
    if (t < 64) {
        float4 p0 = *(const float4*)&part[t][0];
        float4 p1 = *(const float4*)&part[t + 64][0];
        float4 p2 = *(const float4*)&part[t + 128][0];
        float4 p3 = *(const float4*)&part[t + 192][0];
        *(float4*)&sKV[(t >> 4) & 3][(t & 15) << 2] =
            make_float4(p0.x + p1.x + p2.x + p3.x, p0.y + p1.y + p2.y + p3.y,
                        p0.z + p1.z + p2.z + p3.z, p0.w + p1.w + p2.w + p3.w);
    }
    if (slice == 0 && t >= 64 && t < 128) {
        int v = t - 64;
        svs[v] = vsp[0][v] + vsp[1][v] + vsp[2][v] + vsp[3][v];
    }
    __syncthreads();

    // GEMM: 4 c x 128 o = 512 outputs, 2 per thread
    float* Mb = M + (size_t)b * (CK * CO);
#pragma unroll
    for (int rep = 0; rep < 2; ++rep) {
        int idx = t + rep * 256;         // 0..511
        int c = idx >> 7, o = idx & 127;
        float acc = 0.f;
#pragma unroll
        for (int vq = 0; vq < 16; ++vq) {
            float4 kv4 = *(const float4*)&sKV[c][vq * 4];
            float4 w4  = *(const float4*)&sWw[o][vq * 4];
            acc += kv4.x * w4.x + kv4.y * w4.y + kv4.z * w4.z + kv4.w * w4.w;
        }
        Mb[(size_t)(slice * 4 + c) * CO + o] = acc;
    }

    // d: only slice-0 blocks
    if (slice == 0 && t < 128) {
        float acc = bw[t];
#pragma unroll 16
        for (int v = 0; v < 64; ++v) acc += sWw[t][v] * svs[v];
        d[(size_t)b * CO + t] = acc;
    }
}

// ---------------------------------------------------------------------------
// Kernel 5: out[b,o,n] = d[b,o] + rn[n] * sum_c sq[b,c,n] * M[b,c,o].
// Round-7 structure (32-col chunks), stats from deterministic partials.
// grid (128, 8), block 256.
// ---------------------------------------------------------------------------
__global__ __launch_bounds__(256) void out_kernel(
    const float* __restrict__ Yq, const float* __restrict__ statsP,
    const float* __restrict__ gamma, const float* __restrict__ beta,
    const float* __restrict__ M, const float* __restrict__ d,
    float* __restrict__ out)
{
    const int chunk = blockIdx.x;    // 0..127, 32 cols
    const int b     = blockIdx.y;
    __shared__ float sM[CK * CO];    // [c][o] flat, 32 KB
    __shared__ float sq[64][36];     // 32 cols + pad
    __shared__ float pn[8][32];
    __shared__ float rn[32];
    __shared__ float sd[CO];
    __shared__ float sscl[64], sshf[64];

    const int t = threadIdx.x;
    const int n0 = chunk * 32;

#pragma unroll
    for (int r = 0; r < 8; ++r) {
        int idx4 = t + r * 256;
        ((float4*)sM)[idx4] = ((const float4*)(M + (size_t)b * (CK * CO)))[idx4];
    }
    if (t < CO) sd[t] = d[(size_t)b * CO + t];
    if (t < 64) {
        const float* sp = statsP + (size_t)t * 16;   // which = 0 (q)
        float S = 0.f, SS = 0.f;
#pragma unroll
        for (int ns = 0; ns < 8; ++ns) { S += sp[ns]; SS += sp[8 + ns]; }
        float mean = S * (1.f / BN_COUNT);
        float var  = SS * (1.f / BN_COUNT) - mean * mean;
        float scl  = gamma[t] * rsqrtf(var + 1e-5f);
        sscl[t] = scl;
        sshf[t] = beta[t] - mean * scl;
    }
    __syncthreads();   // sscl/sshf ready before sq staging

    const float* Yb = Yq + (size_t)b * (CK * NTOT) + n0;
#pragma unroll
    for (int r = 0; r < 2; ++r) {
        int idx4 = t + r * 256;        // 0..511
        int c  = idx4 >> 3;            // 0..63
        int j4 = (idx4 & 7) << 2;      // 0..28
        float4 xv = *(const float4*)(Yb + (size_t)c * NTOT + j4);
        float scl = sscl[c], sh = sshf[c];
        sq[c][j4 + 0] = xv.x * scl + sh;
        sq[c][j4 + 1] = xv.y * scl + sh;
        sq[c][j4 + 2] = xv.z * scl + sh;
        sq[c][j4 + 3] = xv.w * scl + sh;
    }
    __syncthreads();

    // Parallel norm partials: group g (of 8) sums channels g*8..+8 per col
    {
        const int col = t & 31, g = t >> 5;
        float s = 0.f;
#pragma unroll
        for (int i = 0; i < 8; ++i) { float x = sq[g * 8 + i][col]; s += x * x; }
        pn[g][col] = s;
    }
    __syncthreads();
    if (t < 32) {
        float s2 = pn[0][t] + pn[1][t] + pn[2][t] + pn[3][t]
                 + pn[4][t] + pn[5][t] + pn[6][t] + pn[7][t];
        rn[t] = 1.f / (sqrtf(s2) + 1e-7f);
    }
    __syncthreads();

    const int j0 = (t & 7) << 2;        // 4 columns
    const int o0 = (t >> 3) << 2;       // 4 out-channels
    float acc[4][4];
#pragma unroll
    for (int jj = 0; jj < 4; ++jj)
#pragma unroll
        for (int oo = 0; oo < 4; ++oo) acc[jj][oo] = 0.f;

#pragma unroll 4
    for (int c = 0; c < 64; ++c) {
        float4 qv = *(const float4*)&sq[c][j0];
        float4 m0 = *(const float4*)&sM[c * CO + o0];
        float aq[4] = {qv.x, qv.y, qv.z, qv.w};
        float am[4] = {m0.x, m0.y, m0.z, m0.w};
#pragma unroll
        for (int jj = 0; jj < 4; ++jj)
#pragma unroll
            for (int oo = 0; oo < 4; ++oo) acc[jj][oo] += aq[jj] * am[oo];
    }

    float4 rq = *(const float4*)&rn[j0];   // per-thread column norms

    float* outb = out + (size_t)b * (CO * NTOT) + n0;
#pragma unroll
    for (int oo = 0; oo < 4; ++oo) {
        float dd = sd[o0 + oo];
        float4 st = make_float4(acc[0][oo] * rq.x + dd,
                                acc[1][oo] * rq.y + dd,
                                acc[2][oo] * rq.z + dd,
                                acc[3][oo] * rq.w + dd);
        *(float4*)&outb[(size_t)(o0 + oo) * NTOT + j0] = st;
    }
}

// ---------------------------------------------------------------------------
extern "C" void kernel_launch(void* const* d_in, const int* in_sizes, int n_in,
                              void* d_out, int out_size, void* d_ws, size_t ws_size,
                              hipStream_t stream) {
    (void)in_sizes; (void)n_in; (void)out_size; (void)ws_size;
    const float* q     = (const float*)d_in[0];
    const float* k     = (const float*)d_in[1];
    const float* v     = (const float*)d_in[2];
    const float* Wk    = (const float*)d_in[3];
    const float* bk    = (const float*)d_in[4];
    const float* gamma = (const float*)d_in[5];
    const float* beta  = (const float*)d_in[6];
    const float* Wv    = (const float*)d_in[7];
    const float* bv    = (const float*)d_in[8];
    const float* Ww    = (const float*)d_in[9];
    const float* bw    = (const float*)d_in[10];
    float* out = (float*)d_out;
    float* ws  = (float*)d_ws;

    float* Yq    = ws + OFF_YQ;
    float* Yk    = ws + OFF_YK;
    float* Vv    = ws + OFF_V;
    float* stats = ws + OFF_STATS;
    float* M     = ws + OFF_M;     // aliases dead Yk region (stream-ordered safe)
    float* dd    = ws + OFF_D;     // aliases dead Yk region
    float* KVp   = out;            // d_out as scratch; fully overwritten by out_kernel
    float* vsumP = out + VSUMP_OFF;

    // No memset: statsP/KVp/vsumP are all fully written deterministically.
    gemm3_kernel<<<dim3(64, NBATCH, 3), 256, 0, stream>>>(
        q, k, v, Wk, bk, Wv, bv, Yq, Yk, Vv);
    stats_kernel<<<dim3(8, 64, 2), 256, 0, stream>>>(Yq, Yk, stats);
    kv_kernel<<<dim3(64, NBATCH), 256, 0, stream>>>(Yk, Vv, stats, gamma, beta, KVp, vsumP);
    m_kernel<<<dim3(16, NBATCH), 256, 0, stream>>>(KVp, vsumP, Ww, bw, M, dd);
    out_kernel<<<dim3(128, NBATCH), 256, 0, stream>>>(Yq, stats, gamma, beta, M, dd, out);
}